// Round 6
// baseline (211.168 us; speedup 1.0000x reference)
//
#include <hip/hip_runtime.h>
#include <math.h>

typedef __attribute__((ext_vector_type(8))) short  short8;
typedef __attribute__((ext_vector_type(4))) float  f32x4;

// Problem constants: N=200000, E=100000, H=100, R=172, T=100
static constexpr int H     = 100;
static constexpr int RD    = 172;
static constexpr int WK    = 472;            // w_ih K
// Padded K layout (8-col chunks):
//  chunks [0,13)   mem[node]  (msg part; copy of hh chunks, has-masked)
//  chunks [13,26)  mem[other]
//  chunks [26,48)  raw_msg
//  chunks [48,64)  time-enc
//  chunks [64,80)  mem[node]  (hh part, always present)
static constexpr int KTOT  = 640;
static constexpr int NKS   = 20;             // K-steps of 32
static constexpr int MB    = 48;             // nodes per block
static constexpr int GRPS  = 3;              // 16-row groups
static constexpr int BLK   = 448;            // 7 waves
static constexpr int SLOTS = 64;             // 16B slots per (grp,ks) tile
// B tiles: [0,7) r (w_hh folded), [7,14) z (folded), [14,21) n-ih (ks<16), [21,28) n-hh (ks>=16)
static constexpr int NTT   = 28;
static constexpr int BPK_N = NTT * NKS * 64 * 8;   // 286720 bf16

__device__ inline unsigned short f2bf(float x) {
    union { float f; unsigned u; } v; v.f = x;
    return (unsigned short)((v.u + 0x7FFFu + ((v.u >> 16) & 1u)) >> 16);
}
__device__ inline float bf2f(unsigned short b) {
    union { unsigned u; float f; } v; v.u = ((unsigned)b) << 16;
    return v.f;
}
__device__ inline unsigned pkbf(float a, float b) {
    unsigned r;
    asm("v_cvt_pk_bf16_f32 %0, %1, %2" : "=v"(r) : "v"(a), "v"(b));
    return r;
}
__device__ inline f32x4 mfma16(short8 a, short8 b, f32x4 c) {
    return __builtin_amdgcn_mfma_f32_16x16x32_bf16(a, b, c, 0, 0, 0);
}
__device__ inline float4 ld4g(const float* base, int lc, int limit) {
    if (lc + 4 <= limit) return *(const float4*)(base + lc);
    return make_float4(0.f, 0.f, 0.f, 0.f);
}

// ---------------- aggregation kernels ----------------
__global__ __launch_bounds__(256) void k_init(int* __restrict__ maxt, int* __restrict__ win, int N) {
    int i = blockIdx.x * blockDim.x + threadIdx.x;
    if (i < N) { maxt[i] = (int)0x80000000; win[i] = -1; }
}

__global__ __launch_bounds__(256) void k_maxt(const int* __restrict__ src, const int* __restrict__ dst,
                                              const int* __restrict__ t, int* __restrict__ maxt, int E) {
    int j = blockIdx.x * blockDim.x + threadIdx.x;
    if (j < E) {
        int tj = t[j];
        atomicMax(&maxt[src[j]], tj);
        atomicMax(&maxt[dst[j]], tj);
    }
}

__global__ __launch_bounds__(256) void k_win(const int* __restrict__ src, const int* __restrict__ dst,
                                             const int* __restrict__ t, const int* __restrict__ maxt,
                                             int* __restrict__ win, int E) {
    int j = blockIdx.x * blockDim.x + threadIdx.x;
    if (j < E) {
        int tj = t[j];
        int s = src[j], d = dst[j];
        if (maxt[s] == tj) atomicMax(&win[s], j);
        if (maxt[d] == tj) atomicMax(&win[d], j + E);
    }
}

__global__ __launch_bounds__(256) void k_lu(const int* __restrict__ last_update, const int* __restrict__ maxt,
                                            float* __restrict__ out_lu, int N) {
    int i = blockIdx.x * blockDim.x + threadIdx.x;
    if (i < N) {
        int m = maxt[i], lu = last_update[i];
        out_lu[i] = (float)(m > lu ? m : lu);
    }
}

// ---------------- weight prep ----------------
__global__ __launch_bounds__(256) void k_prep(const float* __restrict__ w_ih, const float* __restrict__ w_hh,
                                              unsigned short* __restrict__ B) {
    int idx = blockIdx.x * 256 + threadIdx.x;
    if (idx >= BPK_N) return;
    int jj   = idx & 7;
    int lane = (idx >> 3) & 63;
    int rest = idx >> 9;          // tile*NKS + ks
    int ks   = rest % NKS;
    int tile = rest / NKS;
    int kk   = ks * 32 + ((lane >> 4) << 3) + jj;
    float v = 0.f;
    if (tile < 21) {
        int gate = tile / 7;
        int tcol = (tile % 7) * 16 + (lane & 15);
        if (tcol < 100) {
            if (kk < 512) {
                int col = -1;
                if (kk < 100)                   col = kk;          // mem[node]
                else if (kk >= 104 && kk < 204) col = kk - 4;      // mem[other]
                else if (kk >= 208 && kk < 380) col = kk - 8;      // raw
                else if (kk >= 384 && kk < 484) col = kk - 12;     // tenc
                if (col >= 0) v = w_ih[(gate * 100 + tcol) * WK + col];
            } else {
                int khh = kk - 512;
                if (gate < 2 && khh < 100)                          // fold w_hh for r,z
                    v = w_hh[(gate * 100 + tcol) * H + khh];
            }
        }
    } else {
        int tcol = (tile - 21) * 16 + (lane & 15);
        int khh  = kk - 512;
        if (tcol < 100 && khh >= 0 && khh < 100)
            v = w_hh[(200 + tcol) * H + khh];
    }
    B[idx] = f2bf(v);
}

// ---------------- fused GRU via bf16 MFMA ----------------
__global__ __launch_bounds__(BLK, 3) void k_gru(
    const int* __restrict__ src, const int* __restrict__ dst, const int* __restrict__ t,
    const float* __restrict__ raw_msg, const float* __restrict__ memory,
    const int* __restrict__ last_update, const float* __restrict__ te_w,
    const float* __restrict__ te_b, const float* __restrict__ b_ih,
    const float* __restrict__ b_hh, const int* __restrict__ win,
    const unsigned short* __restrict__ Bpack,
    float* __restrict__ out_mem, int E, int N)
{
    __shared__ unsigned short sA[GRPS * NKS * SLOTS * 8];   // 61440 B
    __shared__ int   s_other[MB];
    __shared__ int   s_j[MB];
    __shared__ int   s_has[MB];
    __shared__ float s_dt[MB];

    const int tid   = threadIdx.x;
    const int node0 = blockIdx.x * MB;

    // --- decode winners ---
    if (tid < MB) {
        int node = node0 + tid;
        int has = 0, j = 0, other = 0; float dt = 0.f;
        if (node < N) {
            int w = win[node];
            if (w >= 0) {
                has = 1;
                int e = (w < E) ? w : (w - E);
                j = e;
                other = (w < E) ? dst[e] : src[e];
                dt = (float)(t[e] - last_update[node]);
            }
        }
        s_j[tid] = j; s_other[tid] = other; s_has[tid] = has; s_dt[tid] = dt;
    }
    __syncthreads();

    // --- stage A: 384 threads, fixed node per thread (384 % 48 == 0) ---
    if (tid < 384) {
        const int nl    = tid % 48;
        const int c0    = tid / 48;               // 0..7
        const int node  = node0 + nl;
        const bool valid = node < N;
        const int has   = s_has[nl];
        const float* memN = memory + (size_t)node * H;
        const float* memO = memory + (size_t)s_other[nl] * H;
        const float* rawJ = raw_msg + (size_t)s_j[nl] * RD;
        const float dt  = s_dt[nl];
        const int grp = nl >> 4;
        const int row = nl & 15;

        for (int cc = c0; cc < 67; cc += 8) {
            const int c  = cc + 13;               // chunk 13..79
            const int kb = c * 8;
            float4 va = make_float4(0.f, 0.f, 0.f, 0.f), vb = va;
            if (c < 64) {
                if (has) {
                    if (c < 26)      { va = ld4g(memO, kb - 104, 100); vb = ld4g(memO, kb - 100, 100); }
                    else if (c < 48) { va = ld4g(rawJ, kb - 208, RD ); vb = ld4g(rawJ, kb - 204, RD ); }
                    else {
                        const int lc = kb - 384;
                        float vv[8];
#pragma unroll
                        for (int q = 0; q < 8; ++q) {
                            int col = lc + q;
                            vv[q] = (col < 100) ? __cosf(fmaf(dt, te_w[col], te_b[col])) : 0.f;
                        }
                        va = make_float4(vv[0], vv[1], vv[2], vv[3]);
                        vb = make_float4(vv[4], vv[5], vv[6], vv[7]);
                    }
                }
            } else if (valid) {                   // hh: mem[node]
                va = ld4g(memN, kb - 512, 100);
                vb = ld4g(memN, kb - 508, 100);
            }
            int4 sv;
            sv.x = (int)pkbf(va.x, va.y);
            sv.y = (int)pkbf(va.z, va.w);
            sv.z = (int)pkbf(vb.x, vb.y);
            sv.w = (int)pkbf(vb.z, vb.w);
            {
                const int ks = c >> 2, sub = c & 3;
                const int slot = sub * 16 + (row ^ (sub << 2));
                *(int4*)&sA[((grp * NKS + ks) * SLOTS + slot) * 8] = sv;
            }
            if (c >= 64 && c < 77) {              // msg copy of mem[node], has-masked
                int4 sm_;
                sm_.x = has ? sv.x : 0; sm_.y = has ? sv.y : 0;
                sm_.z = has ? sv.z : 0; sm_.w = has ? sv.w : 0;
                const int cm = c - 64;
                const int ks = cm >> 2, sub = cm & 3;
                const int slot = sub * 16 + (row ^ (sub << 2));
                *(int4*)&sA[((grp * NKS + ks) * SLOTS + slot) * 8] = sm_;
            }
        }
    }
    __syncthreads();

    // --- MFMA: wave wv owns output cols wv*16..wv*16+15 of all 3 gates ---
    const int wv    = tid >> 6;          // 0..6
    const int lane  = tid & 63;
    const int lrow  = lane & 15;
    const int lhi   = lane >> 4;
    const int slotl = lhi * 16 + (lrow ^ (lhi << 2));

    f32x4 ar[GRPS], az[GRPS], an[GRPS], ah[GRPS];
#pragma unroll
    for (int m = 0; m < GRPS; ++m) { ar[m] = (f32x4)0.f; az[m] = (f32x4)0.f; an[m] = (f32x4)0.f; ah[m] = (f32x4)0.f; }

    __builtin_amdgcn_s_setprio(1);
#pragma unroll
    for (int ks = 0; ks < NKS; ++ks) {
        short8 a0 = *(const short8*)&sA[((0 * NKS + ks) * SLOTS + slotl) * 8];
        short8 a1 = *(const short8*)&sA[((1 * NKS + ks) * SLOTS + slotl) * 8];
        short8 a2 = *(const short8*)&sA[((2 * NKS + ks) * SLOTS + slotl) * 8];
        short8 br = *(const short8*)&Bpack[(((size_t)(     wv) * NKS + ks) * 64 + lane) * 8];
        short8 bz = *(const short8*)&Bpack[(((size_t)( 7 + wv) * NKS + ks) * 64 + lane) * 8];
        short8 bn = (ks < 16)
                  ? *(const short8*)&Bpack[(((size_t)(14 + wv) * NKS + ks) * 64 + lane) * 8]
                  : *(const short8*)&Bpack[(((size_t)(21 + wv) * NKS + ks) * 64 + lane) * 8];
        ar[0] = mfma16(a0, br, ar[0]);  ar[1] = mfma16(a1, br, ar[1]);  ar[2] = mfma16(a2, br, ar[2]);
        az[0] = mfma16(a0, bz, az[0]);  az[1] = mfma16(a1, bz, az[1]);  az[2] = mfma16(a2, bz, az[2]);
        if (ks < 16) { an[0] = mfma16(a0, bn, an[0]);  an[1] = mfma16(a1, bn, an[1]);  an[2] = mfma16(a2, bn, an[2]); }
        else         { ah[0] = mfma16(a0, bn, ah[0]);  ah[1] = mfma16(a1, bn, ah[1]);  ah[2] = mfma16(a2, bn, ah[2]); }
    }
    __builtin_amdgcn_s_setprio(0);

    // --- in-register gates + store; h read from staged hh section in LDS ---
    const int c = wv * 16 + lrow;
    if (c < 100) {
        const float br_ = b_ih[c]       + b_hh[c];
        const float bz_ = b_ih[c + 100] + b_hh[c + 100];
        const float bin = b_ih[c + 200];
        const float bhn = b_hh[c + 200];
        const int ksh = 16 + (c >> 5);
        const int sbh = (c >> 3) & 3;
        const int ceh = c & 7;
#pragma unroll
        for (int m = 0; m < GRPS; ++m) {
#pragma unroll
            for (int r = 0; r < 4; ++r) {
                const int node = node0 + m * 16 + lhi * 4 + r;
                if (node < N) {
                    const int rw   = lhi * 4 + r;
                    const int slot = sbh * 16 + (rw ^ (sbh << 2));
                    const float h  = bf2f(sA[((m * NKS + ksh) * SLOTS + slot) * 8 + ceh]);
                    const float rg = 1.f / (1.f + __expf(-(ar[m][r] + br_)));
                    const float zg = 1.f / (1.f + __expf(-(az[m][r] + bz_)));
                    const float xn = an[m][r] + bin + rg * (ah[m][r] + bhn);
                    const float ex = __expf(2.f * fabsf(xn));
                    const float th = copysignf(1.f - 2.f / (ex + 1.f), xn);
                    out_mem[(size_t)node * H + c] = (1.f - zg) * th + zg * h;
                }
            }
        }
    }
}

extern "C" void kernel_launch(void* const* d_in, const int* in_sizes, int n_in,
                              void* d_out, int out_size, void* d_ws, size_t ws_size,
                              hipStream_t stream)
{
    const int*   src         = (const int*)d_in[0];
    const int*   dst         = (const int*)d_in[1];
    const int*   t           = (const int*)d_in[2];
    const float* raw_msg     = (const float*)d_in[3];
    const float* memory      = (const float*)d_in[4];
    const int*   last_update = (const int*)d_in[5];
    const float* te_w        = (const float*)d_in[6];
    const float* te_b        = (const float*)d_in[7];
    const float* w_ih        = (const float*)d_in[8];
    const float* w_hh        = (const float*)d_in[9];
    const float* b_ih        = (const float*)d_in[10];
    const float* b_hh        = (const float*)d_in[11];

    const int E = in_sizes[0];   // 100000
    const int N = in_sizes[5];   // 200000

    float* out    = (float*)d_out;
    float* out_lu = out + (size_t)N * H;

    int* maxt = (int*)d_ws;
    int* win  = maxt + N;
    unsigned short* Bpack = (unsigned short*)(win + N);

    k_init<<<(N + 255) / 256, 256, 0, stream>>>(maxt, win, N);
    k_prep<<<(BPK_N + 255) / 256, 256, 0, stream>>>(w_ih, w_hh, Bpack);
    k_maxt<<<(E + 255) / 256, 256, 0, stream>>>(src, dst, t, maxt, E);
    k_win <<<(E + 255) / 256, 256, 0, stream>>>(src, dst, t, maxt, win, E);
    k_lu  <<<(N + 255) / 256, 256, 0, stream>>>(last_update, maxt, out_lu, N);
    k_gru <<<(N + MB - 1) / MB, BLK, 0, stream>>>(src, dst, t, raw_msg, memory, last_update,
                                                  te_w, te_b, b_ih, b_hh, win, Bpack, out, E, N);
}

// Round 7
// 188.465 us; speedup vs baseline: 1.1205x; 1.1205x over previous
//
#include <hip/hip_runtime.h>
#include <math.h>

typedef __attribute__((ext_vector_type(8))) short  short8;
typedef __attribute__((ext_vector_type(4))) float  f32x4;

// Problem constants: N=200000, E=100000, H=100, R=172, T=100
static constexpr int H     = 100;
static constexpr int RD    = 172;
static constexpr int WK    = 472;            // w_ih K
// Padded K layout (8-col chunks), chunk index c:
//  c [0,13)   mem[node]  (msg part; has-masked copy of hh chunks)
//  c [13,26)  mem[other]
//  c [26,48)  raw_msg
//  c [48,64)  time-enc
//  c [64,80)  mem[node]  (hh part, always present)
static constexpr int NKS   = 20;             // K-steps of 32 (KTOT=640)
static constexpr int MB    = 48;             // nodes per block
static constexpr int GRPS  = 3;              // 16-row groups
static constexpr int BLK   = 448;            // 7 waves
static constexpr int SLOTS = 64;             // 16B slots per (grp,ks) tile
// B tiles: [0,7) r (w_hh folded), [7,14) z (folded), [14,21) n-ih (ks<16), [21,28) n-hh (ks>=16)
static constexpr int NTT   = 28;
static constexpr int BPK_N = NTT * NKS * 64 * 8;   // 286720 bf16

__device__ inline unsigned short f2bf(float x) {
    union { float f; unsigned u; } v; v.f = x;
    return (unsigned short)((v.u + 0x7FFFu + ((v.u >> 16) & 1u)) >> 16);
}
__device__ inline float bf2f(unsigned short b) {
    union { unsigned u; float f; } v; v.u = ((unsigned)b) << 16;
    return v.f;
}
__device__ inline unsigned pkbf(float a, float b) {
    unsigned r;
    asm("v_cvt_pk_bf16_f32 %0, %1, %2" : "=v"(r) : "v"(a), "v"(b));
    return r;
}
__device__ inline f32x4 mfma16(short8 a, short8 b, f32x4 c) {
    return __builtin_amdgcn_mfma_f32_16x16x32_bf16(a, b, c, 0, 0, 0);
}
__device__ inline float4 ld4g(const float* base, int lc, int limit) {
    if (lc + 4 <= limit) return *(const float4*)(base + lc);
    return make_float4(0.f, 0.f, 0.f, 0.f);
}

// ---------------- aggregation kernels ----------------
__global__ __launch_bounds__(256) void k_init(int* __restrict__ maxt, int* __restrict__ win, int N) {
    int i = blockIdx.x * blockDim.x + threadIdx.x;
    if (i < N) { maxt[i] = (int)0x80000000; win[i] = -1; }
}

__global__ __launch_bounds__(256) void k_maxt(const int* __restrict__ src, const int* __restrict__ dst,
                                              const int* __restrict__ t, int* __restrict__ maxt, int E) {
    int j = blockIdx.x * blockDim.x + threadIdx.x;
    if (j < E) {
        int tj = t[j];
        atomicMax(&maxt[src[j]], tj);
        atomicMax(&maxt[dst[j]], tj);
    }
}

__global__ __launch_bounds__(256) void k_win(const int* __restrict__ src, const int* __restrict__ dst,
                                             const int* __restrict__ t, const int* __restrict__ maxt,
                                             int* __restrict__ win, int E) {
    int j = blockIdx.x * blockDim.x + threadIdx.x;
    if (j < E) {
        int tj = t[j];
        int s = src[j], d = dst[j];
        if (maxt[s] == tj) atomicMax(&win[s], j);
        if (maxt[d] == tj) atomicMax(&win[d], j + E);
    }
}

// ---------------- weight prep ----------------
__global__ __launch_bounds__(256) void k_prep(const float* __restrict__ w_ih, const float* __restrict__ w_hh,
                                              unsigned short* __restrict__ B) {
    int idx = blockIdx.x * 256 + threadIdx.x;
    if (idx >= BPK_N) return;
    int jj   = idx & 7;
    int lane = (idx >> 3) & 63;
    int rest = idx >> 9;          // tile*NKS + ks
    int ks   = rest % NKS;
    int tile = rest / NKS;
    int kk   = ks * 32 + ((lane >> 4) << 3) + jj;
    float v = 0.f;
    if (tile < 21) {
        int gate = tile / 7;
        int tcol = (tile % 7) * 16 + (lane & 15);
        if (tcol < 100) {
            if (kk < 512) {
                int col = -1;
                if (kk < 100)                   col = kk;          // mem[node]
                else if (kk >= 104 && kk < 204) col = kk - 4;      // mem[other]
                else if (kk >= 208 && kk < 380) col = kk - 8;      // raw
                else if (kk >= 384 && kk < 484) col = kk - 12;     // tenc
                if (col >= 0) v = w_ih[(gate * 100 + tcol) * WK + col];
            } else {
                int khh = kk - 512;
                if (gate < 2 && khh < 100)                          // fold w_hh for r,z
                    v = w_hh[(gate * 100 + tcol) * H + khh];
            }
        }
    } else {
        int tcol = (tile - 21) * 16 + (lane & 15);
        int khh  = kk - 512;
        if (tcol < 100 && khh >= 0 && khh < 100)
            v = w_hh[(200 + tcol) * H + khh];
    }
    B[idx] = f2bf(v);
}

// ---------------- fused GRU via bf16 MFMA ----------------
__global__ __launch_bounds__(BLK, 4) void k_gru(
    const int* __restrict__ src, const int* __restrict__ dst, const int* __restrict__ t,
    const float* __restrict__ raw_msg, const float* __restrict__ memory,
    const int* __restrict__ last_update, const float* __restrict__ te_w,
    const float* __restrict__ te_b, const float* __restrict__ b_ih,
    const float* __restrict__ b_hh, const int* __restrict__ win,
    const unsigned short* __restrict__ Bpack,
    float* __restrict__ out_mem, float* __restrict__ out_lu, int E, int N)
{
    __shared__ unsigned short sA[GRPS * NKS * SLOTS * 8];   // 61440 B
    __shared__ int   s_other[MB];
    __shared__ int   s_j[MB];
    __shared__ int   s_has[MB];
    __shared__ float s_dt[MB];

    const int tid   = threadIdx.x;
    const int node0 = blockIdx.x * MB;

    // --- decode winners (+ write out_lu, folding the old k_lu kernel) ---
    if (tid < MB) {
        int node = node0 + tid;
        int has = 0, j = 0, other = 0; float dt = 0.f;
        if (node < N) {
            int lu = last_update[node];
            int w  = win[node];
            int te = lu;
            if (w >= 0) {
                has = 1;
                int e = (w < E) ? w : (w - E);
                j = e;
                other = (w < E) ? dst[e] : src[e];
                te = t[e];
                dt = (float)(te - lu);
            }
            out_lu[node] = (float)(te > lu ? te : lu);
        }
        s_j[tid] = j; s_other[tid] = other; s_has[tid] = has; s_dt[tid] = dt;
    }
    __syncthreads();

    // --- stage A with register prefetch (T14): issue ALL loads, then convert+write ---
    if (tid < 432) {                              // 9 chunk-groups x 48 nodes
        const int nl    = tid % 48;
        const int c0    = tid / 48;               // 0..8
        const int node  = node0 + nl;
        const bool valid = node < N;
        const int has   = s_has[nl];
        const float* memN = memory + (size_t)node * H;
        const float* memO = memory + (size_t)s_other[nl] * H;
        const float* rawJ = raw_msg + (size_t)s_j[nl] * RD;
        const float dt  = s_dt[nl];
        const int grp = nl >> 4;
        const int row = nl & 15;

        float4 va[8], vb[8];
        // phase 1: issue loads / compute tenc (no LDS writes -> loads stay in flight)
#pragma unroll
        for (int it = 0; it < 8; ++it) {
            const int cc = c0 + it * 9;
            va[it] = make_float4(0.f, 0.f, 0.f, 0.f); vb[it] = va[it];
            if (cc < 67) {
                const int c  = cc + 13;
                const int kb = c * 8;
                if (c < 64) {
                    if (has) {
                        if (c < 26)      { va[it] = ld4g(memO, kb - 104, 100); vb[it] = ld4g(memO, kb - 100, 100); }
                        else if (c < 48) { va[it] = ld4g(rawJ, kb - 208, RD ); vb[it] = ld4g(rawJ, kb - 204, RD ); }
                        else {
                            const int lc = kb - 384;
                            float vv[8];
#pragma unroll
                            for (int q = 0; q < 8; ++q) {
                                int col = lc + q;
                                vv[q] = (col < 100) ? __cosf(fmaf(dt, te_w[col], te_b[col])) : 0.f;
                            }
                            va[it] = make_float4(vv[0], vv[1], vv[2], vv[3]);
                            vb[it] = make_float4(vv[4], vv[5], vv[6], vv[7]);
                        }
                    }
                } else if (valid) {               // hh: mem[node]
                    va[it] = ld4g(memN, kb - 512, 100);
                    vb[it] = ld4g(memN, kb - 508, 100);
                }
            }
        }
        // phase 2: convert + LDS write
#pragma unroll
        for (int it = 0; it < 8; ++it) {
            const int cc = c0 + it * 9;
            if (cc < 67) {
                const int c = cc + 13;
                int4 sv;
                sv.x = (int)pkbf(va[it].x, va[it].y);
                sv.y = (int)pkbf(va[it].z, va[it].w);
                sv.z = (int)pkbf(vb[it].x, vb[it].y);
                sv.w = (int)pkbf(vb[it].z, vb[it].w);
                {
                    const int ks = c >> 2, sub = c & 3;
                    const int slot = sub * 16 + (row ^ (sub << 2));
                    *(int4*)&sA[((grp * NKS + ks) * SLOTS + slot) * 8] = sv;
                }
                if (c >= 64 && c < 77) {          // msg copy of mem[node], has-masked
                    int4 sm_;
                    sm_.x = has ? sv.x : 0; sm_.y = has ? sv.y : 0;
                    sm_.z = has ? sv.z : 0; sm_.w = has ? sv.w : 0;
                    const int cm = c - 64;
                    const int ks = cm >> 2, sub = cm & 3;
                    const int slot = sub * 16 + (row ^ (sub << 2));
                    *(int4*)&sA[((grp * NKS + ks) * SLOTS + slot) * 8] = sm_;
                }
            }
        }
    }
    __syncthreads();

    // --- MFMA: wave wv owns output cols wv*16..wv*16+15 of all 3 gates ---
    const int wv    = tid >> 6;          // 0..6
    const int lane  = tid & 63;
    const int lrow  = lane & 15;
    const int lhi   = lane >> 4;
    const int slotl = lhi * 16 + (lrow ^ (lhi << 2));

    f32x4 ar[GRPS], az[GRPS], an[GRPS], ah[GRPS];
#pragma unroll
    for (int m = 0; m < GRPS; ++m) { ar[m] = (f32x4)0.f; az[m] = (f32x4)0.f; an[m] = (f32x4)0.f; ah[m] = (f32x4)0.f; }

    __builtin_amdgcn_s_setprio(1);
#pragma unroll
    for (int ks = 0; ks < NKS; ++ks) {
        short8 a0 = *(const short8*)&sA[((0 * NKS + ks) * SLOTS + slotl) * 8];
        short8 a1 = *(const short8*)&sA[((1 * NKS + ks) * SLOTS + slotl) * 8];
        short8 a2 = *(const short8*)&sA[((2 * NKS + ks) * SLOTS + slotl) * 8];
        short8 br = *(const short8*)&Bpack[(((size_t)(     wv) * NKS + ks) * 64 + lane) * 8];
        short8 bz = *(const short8*)&Bpack[(((size_t)( 7 + wv) * NKS + ks) * 64 + lane) * 8];
        short8 bn = (ks < 16)
                  ? *(const short8*)&Bpack[(((size_t)(14 + wv) * NKS + ks) * 64 + lane) * 8]
                  : *(const short8*)&Bpack[(((size_t)(21 + wv) * NKS + ks) * 64 + lane) * 8];
        ar[0] = mfma16(a0, br, ar[0]);  ar[1] = mfma16(a1, br, ar[1]);  ar[2] = mfma16(a2, br, ar[2]);
        az[0] = mfma16(a0, bz, az[0]);  az[1] = mfma16(a1, bz, az[1]);  az[2] = mfma16(a2, bz, az[2]);
        if (ks < 16) { an[0] = mfma16(a0, bn, an[0]);  an[1] = mfma16(a1, bn, an[1]);  an[2] = mfma16(a2, bn, an[2]); }
        else         { ah[0] = mfma16(a0, bn, ah[0]);  ah[1] = mfma16(a1, bn, ah[1]);  ah[2] = mfma16(a2, bn, ah[2]); }
    }
    __builtin_amdgcn_s_setprio(0);

    // --- in-register gates + store; h read from staged hh section in LDS ---
    const int c = wv * 16 + lrow;
    if (c < 100) {
        const float br_ = b_ih[c]       + b_hh[c];
        const float bz_ = b_ih[c + 100] + b_hh[c + 100];
        const float bin = b_ih[c + 200];
        const float bhn = b_hh[c + 200];
        const int ksh = 16 + (c >> 5);
        const int sbh = (c >> 3) & 3;
        const int ceh = c & 7;
#pragma unroll
        for (int m = 0; m < GRPS; ++m) {
#pragma unroll
            for (int r = 0; r < 4; ++r) {
                const int node = node0 + m * 16 + lhi * 4 + r;
                if (node < N) {
                    const int rw   = lhi * 4 + r;
                    const int slot = sbh * 16 + (rw ^ (sbh << 2));
                    const float h  = bf2f(sA[((m * NKS + ksh) * SLOTS + slot) * 8 + ceh]);
                    const float rg = 1.f / (1.f + __expf(-(ar[m][r] + br_)));
                    const float zg = 1.f / (1.f + __expf(-(az[m][r] + bz_)));
                    const float xn = an[m][r] + bin + rg * (ah[m][r] + bhn);
                    const float ex = __expf(2.f * fabsf(xn));
                    const float th = copysignf(1.f - 2.f / (ex + 1.f), xn);
                    out_mem[(size_t)node * H + c] = (1.f - zg) * th + zg * h;
                }
            }
        }
    }
}

extern "C" void kernel_launch(void* const* d_in, const int* in_sizes, int n_in,
                              void* d_out, int out_size, void* d_ws, size_t ws_size,
                              hipStream_t stream)
{
    const int*   src         = (const int*)d_in[0];
    const int*   dst         = (const int*)d_in[1];
    const int*   t           = (const int*)d_in[2];
    const float* raw_msg     = (const float*)d_in[3];
    const float* memory      = (const float*)d_in[4];
    const int*   last_update = (const int*)d_in[5];
    const float* te_w        = (const float*)d_in[6];
    const float* te_b        = (const float*)d_in[7];
    const float* w_ih        = (const float*)d_in[8];
    const float* w_hh        = (const float*)d_in[9];
    const float* b_ih        = (const float*)d_in[10];
    const float* b_hh        = (const float*)d_in[11];

    const int E = in_sizes[0];   // 100000
    const int N = in_sizes[5];   // 200000

    float* out    = (float*)d_out;
    float* out_lu = out + (size_t)N * H;

    int* maxt = (int*)d_ws;
    int* win  = maxt + N;
    unsigned short* Bpack = (unsigned short*)(win + N);

    k_init<<<(N + 255) / 256, 256, 0, stream>>>(maxt, win, N);
    k_prep<<<(BPK_N + 255) / 256, 256, 0, stream>>>(w_ih, w_hh, Bpack);
    k_maxt<<<(E + 255) / 256, 256, 0, stream>>>(src, dst, t, maxt, E);
    k_win <<<(E + 255) / 256, 256, 0, stream>>>(src, dst, t, maxt, win, E);
    k_gru <<<(N + MB - 1) / MB, BLK, 0, stream>>>(src, dst, t, raw_msg, memory, last_update,
                                                  te_w, te_b, b_ih, b_hh, win, Bpack,
                                                  out, out_lu, E, N);
}